// Round 1
// baseline (1687.030 us; speedup 1.0000x reference)
//
#include <hip/hip_runtime.h>

#define L_SEQ 2048
#define NH    16
#define E_DIM 1024
#define M_ROWS 4096

typedef unsigned short u16;
typedef unsigned int   u32;
typedef __attribute__((ext_vector_type(8))) __bf16 bf16x8;
typedef __attribute__((ext_vector_type(4))) float  f32x4;

__device__ __forceinline__ u16 f2bf(float f) {
  union { float f; u32 u; } x; x.f = f;
  u32 u = x.u;
  return (u16)((u + 0x7FFFu + ((u >> 16) & 1u)) >> 16);
}
__device__ __forceinline__ float bf2f(u16 v) {
  union { u32 u; float f; } x; x.u = ((u32)v) << 16;
  return x.f;
}
__device__ __forceinline__ void st_bf4(u16* p, float a, float b, float c, float d) {
  ushort4 u; u.x = f2bf(a); u.y = f2bf(b); u.z = f2bf(c); u.w = f2bf(d);
  *reinterpret_cast<ushort4*>(p) = u;
}

// ---------------- LayerNorm: fp32 input -> 3 bf16 outputs (stats computed once) ----------------
__global__ __launch_bounds__(256) void ln3_kernel(
    const float* __restrict__ x,
    const float* __restrict__ g0, const float* __restrict__ b0, u16* __restrict__ o0,
    const float* __restrict__ g1, const float* __restrict__ b1, u16* __restrict__ o1,
    const float* __restrict__ g2, const float* __restrict__ b2, u16* __restrict__ o2)
{
  __shared__ float red[8];
  const size_t row = blockIdx.x;
  const int t = threadIdx.x;
  float4 v = reinterpret_cast<const float4*>(x + row * E_DIM)[t];
  float s = v.x + v.y + v.z + v.w;
  float q = v.x*v.x + v.y*v.y + v.z*v.z + v.w*v.w;
  #pragma unroll
  for (int o = 32; o; o >>= 1) { s += __shfl_down(s, o); q += __shfl_down(q, o); }
  if ((t & 63) == 0) { red[t >> 6] = s; red[4 + (t >> 6)] = q; }
  __syncthreads();
  float S = red[0] + red[1] + red[2] + red[3];
  float Q = red[4] + red[5] + red[6] + red[7];
  float mean = S * (1.f / E_DIM);
  float rstd = rsqrtf(Q * (1.f / E_DIM) - mean * mean + 1e-5f);
  float n0 = (v.x - mean) * rstd, n1 = (v.y - mean) * rstd;
  float n2 = (v.z - mean) * rstd, n3 = (v.w - mean) * rstd;
  const int c = t * 4;
  {
    float4 g = *reinterpret_cast<const float4*>(g0 + c);
    float4 b = *reinterpret_cast<const float4*>(b0 + c);
    st_bf4(o0 + row * E_DIM + c, n0*g.x + b.x, n1*g.y + b.y, n2*g.z + b.z, n3*g.w + b.w);
  }
  {
    float4 g = *reinterpret_cast<const float4*>(g1 + c);
    float4 b = *reinterpret_cast<const float4*>(b1 + c);
    st_bf4(o1 + row * E_DIM + c, n0*g.x + b.x, n1*g.y + b.y, n2*g.z + b.z, n3*g.w + b.w);
  }
  {
    float4 g = *reinterpret_cast<const float4*>(g2 + c);
    float4 b = *reinterpret_cast<const float4*>(b2 + c);
    st_bf4(o2 + row * E_DIM + c, n0*g.x + b.x, n1*g.y + b.y, n2*g.z + b.z, n3*g.w + b.w);
  }
}

// ---------------- LayerNorm: bf16 input -> bf16 output ----------------
__global__ __launch_bounds__(256) void ln1_bf_kernel(
    const u16* __restrict__ x, const float* __restrict__ g,
    const float* __restrict__ b, u16* __restrict__ o)
{
  __shared__ float red[8];
  const size_t row = blockIdx.x;
  const int t = threadIdx.x;
  ushort4 u = reinterpret_cast<const ushort4*>(x + row * E_DIM)[t];
  float v0 = bf2f(u.x), v1 = bf2f(u.y), v2 = bf2f(u.z), v3 = bf2f(u.w);
  float s = v0 + v1 + v2 + v3;
  float q = v0*v0 + v1*v1 + v2*v2 + v3*v3;
  #pragma unroll
  for (int off = 32; off; off >>= 1) { s += __shfl_down(s, off); q += __shfl_down(q, off); }
  if ((t & 63) == 0) { red[t >> 6] = s; red[4 + (t >> 6)] = q; }
  __syncthreads();
  float S = red[0] + red[1] + red[2] + red[3];
  float Q = red[4] + red[5] + red[6] + red[7];
  float mean = S * (1.f / E_DIM);
  float rstd = rsqrtf(Q * (1.f / E_DIM) - mean * mean + 1e-5f);
  const int c = t * 4;
  float4 gg = *reinterpret_cast<const float4*>(g + c);
  float4 bb = *reinterpret_cast<const float4*>(b + c);
  st_bf4(o + row * E_DIM + c,
         (v0 - mean)*rstd*gg.x + bb.x, (v1 - mean)*rstd*gg.y + bb.y,
         (v2 - mean)*rstd*gg.z + bb.z, (v3 - mean)*rstd*gg.w + bb.w);
}

// ---------------- Weight transpose + fp32->bf16: W (K x N) -> WT (N x K) ----------------
__global__ __launch_bounds__(256) void transpose_w(const float* __restrict__ W, u16* __restrict__ WT)
{
  __shared__ float tile[32][33];
  const int tx = threadIdx.x & 31, ty = threadIdx.x >> 5;  // ty in [0,8)
  const int bx = blockIdx.x * 32, by = blockIdx.y * 32;
  #pragma unroll
  for (int r = 0; r < 4; ++r)
    tile[ty + r * 8][tx] = W[(size_t)(by + ty + r * 8) * E_DIM + bx + tx];
  __syncthreads();
  #pragma unroll
  for (int r = 0; r < 4; ++r)
    WT[(size_t)(bx + ty + r * 8) * E_DIM + by + tx] = f2bf(tile[tx][ty + r * 8]);
}

// ---------------- bf16 MFMA GEMM: C(M x 1024) = A(M x 1024) * BT(1024 x 1024)^T + bias ----------------
// MODE 0: q     -> bf16 out, layout (N,H,L,Dh)
// MODE 1: k out -> fp32 out, layout (N,H,Dh,L)
// MODE 2: v out -> fp32 out, layout (N,H,L,Dh)
// MODE 3: final -> fp32 out, row-major (M x 1024), += tokens
#define BK 32
template<int MODE>
__global__ __launch_bounds__(256) void gemm_bt(
    const u16* __restrict__ A, const u16* __restrict__ BT, const float* __restrict__ bias,
    float* __restrict__ outf, u16* __restrict__ outb, const float* __restrict__ extra)
{
  __shared__ u16 Alds[128 * BK];
  __shared__ u16 Blds[128 * BK];
  const int t = threadIdx.x;
  const int lane = t & 63, wave = t >> 6;
  const int wm = wave >> 1, wn = wave & 1;
  const int m0 = blockIdx.y * 128;
  const int n0 = blockIdx.x * 128;

  f32x4 acc[4][4] = {};

  for (int kt = 0; kt < E_DIM; kt += BK) {
    #pragma unroll
    for (int s = 0; s < 2; ++s) {
      const int seg = t + s * 256;            // 512 x 16B segments per tile
      const int r = seg >> 2, k0 = (seg & 3) * 8;
      uint4 av = *reinterpret_cast<const uint4*>(A  + (size_t)(m0 + r) * E_DIM + kt + k0);
      uint4 bv = *reinterpret_cast<const uint4*>(BT + (size_t)(n0 + r) * E_DIM + kt + k0);
      *reinterpret_cast<uint4*>(Alds + seg * 8) = av;
      *reinterpret_cast<uint4*>(Blds + seg * 8) = bv;
    }
    __syncthreads();
    const int fr = lane & 15, ko = (lane >> 4) * 8;
    bf16x8 af[4], bfr[4];
    #pragma unroll
    for (int i = 0; i < 4; ++i) {
      af[i]  = *reinterpret_cast<const bf16x8*>(&Alds[(wm * 64 + i * 16 + fr) * BK + ko]);
      bfr[i] = *reinterpret_cast<const bf16x8*>(&Blds[(wn * 64 + i * 16 + fr) * BK + ko]);
    }
    #pragma unroll
    for (int i = 0; i < 4; ++i)
      #pragma unroll
      for (int j = 0; j < 4; ++j)
        acc[i][j] = __builtin_amdgcn_mfma_f32_16x16x32_bf16(af[i], bfr[j], acc[i][j], 0, 0, 0);
    __syncthreads();
  }

  // epilogue: C/D layout col = lane&15, row = (lane>>4)*4 + reg   [m89-verified]
  const int colb = lane & 15;
  const int rowb = (lane >> 4) * 4;
  #pragma unroll
  for (int i = 0; i < 4; ++i) {
    const int mbase = m0 + wm * 64 + i * 16 + rowb;
    #pragma unroll
    for (int j = 0; j < 4; ++j) {
      const int ncol = n0 + wn * 64 + j * 16 + colb;
      const float bval = bias[ncol];
      #pragma unroll
      for (int r = 0; r < 4; ++r) {
        const int m = mbase + r;
        const float val = acc[i][j][r] + bval;
        const int b = m >> 11, l = m & 2047, h = ncol >> 6, d = ncol & 63;
        if (MODE == 0) {
          outb[(((size_t)(b * NH + h) * L_SEQ + l) << 6) + d] = f2bf(val);
        } else if (MODE == 1) {
          outf[((size_t)((b * NH + h) * 64 + d)) * L_SEQ + l] = val;
        } else if (MODE == 2) {
          outf[(((size_t)(b * NH + h) * L_SEQ + l)) * 64 + d] = val;
        } else {
          outf[(size_t)m * E_DIM + ncol] = val + extra[(size_t)m * E_DIM + ncol];
        }
      }
    }
  }
}

// ---------------- causal attention, one block per (b,h,query-row), fp32 ----------------
// q: bf16 (N,H,L,Dh); k: fp32 (N,H,Dh,L) [d_out]; v: fp32 (N,H,L,Dh) [d_out]
// wv out: bf16 (N,L,H*Dh)
__global__ __launch_bounds__(256) void attn_kernel(
    const u16* __restrict__ qbf, const float* __restrict__ kx,
    const float* __restrict__ vx, u16* __restrict__ wv)
{
  __shared__ float qs[64];
  __shared__ float sc[L_SEQ];
  __shared__ float part[256];
  __shared__ float red[8];
  const int idx = blockIdx.x;
  const int i  = idx & (L_SEQ - 1);
  const int bh = idx >> 11;                 // b*NH + h
  const int t = threadIdx.x;
  const u16* qp = qbf + ((size_t)bh * L_SEQ + i) * 64;
  if (t < 64) qs[t] = bf2f(qp[t]);
  __syncthreads();
  const int cnt = i + 1;
  const float* kp = kx + (size_t)bh * 64 * L_SEQ;
  float lmax = -1e30f;
  for (int j = t; j < cnt; j += 256) {
    float dot = 0.f;
    #pragma unroll 16
    for (int d = 0; d < 64; ++d) dot += qs[d] * kp[(size_t)d * L_SEQ + j];
    float sj = dot * 0.125f;
    sc[j] = sj;
    lmax = fmaxf(lmax, sj);
  }
  #pragma unroll
  for (int o = 32; o; o >>= 1) lmax = fmaxf(lmax, __shfl_down(lmax, o));
  if ((t & 63) == 0) red[t >> 6] = lmax;
  __syncthreads();
  const float m = fmaxf(fmaxf(red[0], red[1]), fmaxf(red[2], red[3]));
  float lsum = 0.f;
  for (int j = t; j < cnt; j += 256) {
    float p = __expf(sc[j] - m);
    sc[j] = p;
    lsum += p;
  }
  #pragma unroll
  for (int o = 32; o; o >>= 1) lsum += __shfl_down(lsum, o);
  if ((t & 63) == 0) red[4 + (t >> 6)] = lsum;
  __syncthreads();
  const float rs = 1.f / (red[4] + red[5] + red[6] + red[7]);
  // PV: wave g handles j === g (mod 4); 64 lanes = 64 d, coalesced v reads
  const float* vp = vx + (size_t)bh * L_SEQ * 64;
  const int d = t & 63, g = t >> 6;
  float accv = 0.f;
  for (int j = g; j < cnt; j += 4)
    accv += sc[j] * vp[(size_t)j * 64 + d];
  part[t] = accv;
  __syncthreads();
  if (t < 64) {
    float val = (part[t] + part[64 + t] + part[128 + t] + part[192 + t]) * rs;
    wv[((size_t)((bh >> 4) * L_SEQ + i)) * E_DIM + (bh & 15) * 64 + t] = f2bf(val);
  }
}

extern "C" void kernel_launch(void* const* d_in, const int* in_sizes, int n_in,
                              void* d_out, int out_size, void* d_ws, size_t ws_size,
                              hipStream_t stream) {
  (void)in_sizes; (void)n_in; (void)out_size; (void)ws_size;
  const float* tokens = (const float*)d_in[0];
  const float* ln_q_g = (const float*)d_in[1];
  const float* ln_q_b = (const float*)d_in[2];
  const float* Wq     = (const float*)d_in[3];
  const float* bq     = (const float*)d_in[4];
  const float* ln_k_g = (const float*)d_in[5];
  const float* ln_k_b = (const float*)d_in[6];
  const float* Wk     = (const float*)d_in[7];
  const float* bk     = (const float*)d_in[8];
  const float* ln_v_g = (const float*)d_in[9];
  const float* ln_v_b = (const float*)d_in[10];
  const float* Wv     = (const float*)d_in[11];
  const float* bv     = (const float*)d_in[12];
  const float* ln_o_g = (const float*)d_in[13];
  const float* ln_o_b = (const float*)d_in[14];
  const float* Wo     = (const float*)d_in[15];
  const float* bo     = (const float*)d_in[16];

  float* out  = (float*)d_out;            // (2,2048,1024)
  float* kout = out + 4194304;            // (2,16,64,2048)
  float* vout = kout + 4194304;           // (2,16,2048,64)

  char* w = (char*)d_ws;
  const size_t MB = (size_t)1 << 20;
  u16* WTq = (u16*)(w + 0 * MB);
  u16* WTv = (u16*)(w + 2 * MB);
  u16* WTk = (u16*)(w + 4 * MB);
  u16* WTo = (u16*)(w + 6 * MB);
  u16* xq  = (u16*)(w + 8 * MB);
  u16* xk  = (u16*)(w + 16 * MB);   // LN with ln_v params (feeds k = x @ Wv)
  u16* xv  = (u16*)(w + 24 * MB);   // LN with ln_k params (feeds v = x @ Wk)
  u16* qbf = (u16*)(w + 32 * MB);
  u16* wvb = (u16*)(w + 40 * MB);
  u16* lnw = (u16*)(w + 48 * MB);

  transpose_w<<<dim3(32, 32), 256, 0, stream>>>(Wq, WTq);
  transpose_w<<<dim3(32, 32), 256, 0, stream>>>(Wv, WTv);
  transpose_w<<<dim3(32, 32), 256, 0, stream>>>(Wk, WTk);
  transpose_w<<<dim3(32, 32), 256, 0, stream>>>(Wo, WTo);
  ln3_kernel<<<M_ROWS, 256, 0, stream>>>(tokens,
      ln_q_g, ln_q_b, xq,
      ln_v_g, ln_v_b, xk,
      ln_k_g, ln_k_b, xv);
  gemm_bt<0><<<dim3(8, 32), 256, 0, stream>>>(xq, WTq, bq, nullptr, qbf, nullptr);
  gemm_bt<1><<<dim3(8, 32), 256, 0, stream>>>(xk, WTv, bv, kout, nullptr, nullptr);
  gemm_bt<2><<<dim3(8, 32), 256, 0, stream>>>(xv, WTk, bk, vout, nullptr, nullptr);
  attn_kernel<<<M_ROWS * NH, 256, 0, stream>>>(qbf, kout, vout, wvb);
  ln1_bf_kernel<<<M_ROWS, 256, 0, stream>>>(wvb, ln_o_g, ln_o_b, lnw);
  gemm_bt<3><<<dim3(8, 32), 256, 0, stream>>>(lnw, WTo, bo, out, nullptr, tokens);
}

// Round 3
// 221.474 us; speedup vs baseline: 7.6173x; 7.6173x over previous
//
#include <hip/hip_runtime.h>

#define L_SEQ 2048
#define NH    16
#define E_DIM 1024
#define M_ROWS 4096

typedef unsigned short u16;
typedef unsigned int   u32;
typedef __attribute__((ext_vector_type(8))) __bf16 bf16x8;
typedef __attribute__((ext_vector_type(4))) float  f32x4;

__device__ __forceinline__ u16 f2bf(float f) {
  union { float f; u32 u; } x; x.f = f;
  u32 u = x.u;
  return (u16)((u + 0x7FFFu + ((u >> 16) & 1u)) >> 16);
}
__device__ __forceinline__ float bf2f(u16 v) {
  union { u32 u; float f; } x; x.u = ((u32)v) << 16;
  return x.f;
}
__device__ __forceinline__ void st_bf4(u16* p, float a, float b, float c, float d) {
  ushort4 u; u.x = f2bf(a); u.y = f2bf(b); u.z = f2bf(c); u.w = f2bf(d);
  *reinterpret_cast<ushort4*>(p) = u;
}

// ---------------- LayerNorm: fp32 input -> 3 bf16 outputs (stats computed once) ----------------
__global__ __launch_bounds__(256) void ln3_kernel(
    const float* __restrict__ x,
    const float* __restrict__ g0, const float* __restrict__ b0, u16* __restrict__ o0,
    const float* __restrict__ g1, const float* __restrict__ b1, u16* __restrict__ o1,
    const float* __restrict__ g2, const float* __restrict__ b2, u16* __restrict__ o2)
{
  __shared__ float red[8];
  const size_t row = blockIdx.x;
  const int t = threadIdx.x;
  float4 v = reinterpret_cast<const float4*>(x + row * E_DIM)[t];
  float s = v.x + v.y + v.z + v.w;
  float q = v.x*v.x + v.y*v.y + v.z*v.z + v.w*v.w;
  #pragma unroll
  for (int o = 32; o; o >>= 1) { s += __shfl_down(s, o); q += __shfl_down(q, o); }
  if ((t & 63) == 0) { red[t >> 6] = s; red[4 + (t >> 6)] = q; }
  __syncthreads();
  float S = red[0] + red[1] + red[2] + red[3];
  float Q = red[4] + red[5] + red[6] + red[7];
  float mean = S * (1.f / E_DIM);
  float rstd = rsqrtf(Q * (1.f / E_DIM) - mean * mean + 1e-5f);
  float n0 = (v.x - mean) * rstd, n1 = (v.y - mean) * rstd;
  float n2 = (v.z - mean) * rstd, n3 = (v.w - mean) * rstd;
  const int c = t * 4;
  {
    float4 g = *reinterpret_cast<const float4*>(g0 + c);
    float4 b = *reinterpret_cast<const float4*>(b0 + c);
    st_bf4(o0 + row * E_DIM + c, n0*g.x + b.x, n1*g.y + b.y, n2*g.z + b.z, n3*g.w + b.w);
  }
  {
    float4 g = *reinterpret_cast<const float4*>(g1 + c);
    float4 b = *reinterpret_cast<const float4*>(b1 + c);
    st_bf4(o1 + row * E_DIM + c, n0*g.x + b.x, n1*g.y + b.y, n2*g.z + b.z, n3*g.w + b.w);
  }
  {
    float4 g = *reinterpret_cast<const float4*>(g2 + c);
    float4 b = *reinterpret_cast<const float4*>(b2 + c);
    st_bf4(o2 + row * E_DIM + c, n0*g.x + b.x, n1*g.y + b.y, n2*g.z + b.z, n3*g.w + b.w);
  }
}

// ---------------- LayerNorm: bf16 input -> bf16 output ----------------
__global__ __launch_bounds__(256) void ln1_bf_kernel(
    const u16* __restrict__ x, const float* __restrict__ g,
    const float* __restrict__ b, u16* __restrict__ o)
{
  __shared__ float red[8];
  const size_t row = blockIdx.x;
  const int t = threadIdx.x;
  ushort4 u = reinterpret_cast<const ushort4*>(x + row * E_DIM)[t];
  float v0 = bf2f(u.x), v1 = bf2f(u.y), v2 = bf2f(u.z), v3 = bf2f(u.w);
  float s = v0 + v1 + v2 + v3;
  float q = v0*v0 + v1*v1 + v2*v2 + v3*v3;
  #pragma unroll
  for (int off = 32; off; off >>= 1) { s += __shfl_down(s, off); q += __shfl_down(q, off); }
  if ((t & 63) == 0) { red[t >> 6] = s; red[4 + (t >> 6)] = q; }
  __syncthreads();
  float S = red[0] + red[1] + red[2] + red[3];
  float Q = red[4] + red[5] + red[6] + red[7];
  float mean = S * (1.f / E_DIM);
  float rstd = rsqrtf(Q * (1.f / E_DIM) - mean * mean + 1e-5f);
  const int c = t * 4;
  float4 gg = *reinterpret_cast<const float4*>(g + c);
  float4 bb = *reinterpret_cast<const float4*>(b + c);
  st_bf4(o + row * E_DIM + c,
         (v0 - mean)*rstd*gg.x + bb.x, (v1 - mean)*rstd*gg.y + bb.y,
         (v2 - mean)*rstd*gg.z + bb.z, (v3 - mean)*rstd*gg.w + bb.w);
}

// ---------------- Weight transpose + fp32->bf16: W (K x N) -> WT (N x K) ----------------
__global__ __launch_bounds__(256) void transpose_w(const float* __restrict__ W, u16* __restrict__ WT)
{
  __shared__ float tile[32][33];
  const int tx = threadIdx.x & 31, ty = threadIdx.x >> 5;  // ty in [0,8)
  const int bx = blockIdx.x * 32, by = blockIdx.y * 32;
  #pragma unroll
  for (int r = 0; r < 4; ++r)
    tile[ty + r * 8][tx] = W[(size_t)(by + ty + r * 8) * E_DIM + bx + tx];
  __syncthreads();
  #pragma unroll
  for (int r = 0; r < 4; ++r)
    WT[(size_t)(bx + ty + r * 8) * E_DIM + by + tx] = f2bf(tile[tx][ty + r * 8]);
}

// ---------------- bf16 MFMA GEMM: C(M x 1024) = A(M x 1024) * BT(1024 x 1024)^T + bias ----------------
// MODE 0: q     -> bf16 out (N,H,L,Dh)
// MODE 1: k     -> fp32 out (N,H,Dh,L)  + bf16 copy (N,H,L,Dh)
// MODE 2: v     -> fp32 out (N,H,L,Dh)  + bf16 V^T  (N,H,64,L)
// MODE 3: final -> fp32 out row-major (M x 1024), += tokens
#define BK 32
template<int MODE>
__global__ __launch_bounds__(256) void gemm_bt(
    const u16* __restrict__ A, const u16* __restrict__ BT, const float* __restrict__ bias,
    float* __restrict__ outf, u16* __restrict__ outb, const float* __restrict__ extra)
{
  __shared__ u16 Alds[128 * BK];
  __shared__ u16 Blds[128 * BK];
  const int t = threadIdx.x;
  const int lane = t & 63, wave = t >> 6;
  const int wm = wave >> 1, wn = wave & 1;
  const int m0 = blockIdx.y * 128;
  const int n0 = blockIdx.x * 128;

  f32x4 acc[4][4] = {};

  for (int kt = 0; kt < E_DIM; kt += BK) {
    #pragma unroll
    for (int s = 0; s < 2; ++s) {
      const int seg = t + s * 256;            // 512 x 16B segments per tile (128 rows x 32 cols)
      const int r = seg >> 2, k0 = (seg & 3) * 8;
      uint4 av = *reinterpret_cast<const uint4*>(A  + (size_t)(m0 + r) * E_DIM + kt + k0);
      uint4 bv = *reinterpret_cast<const uint4*>(BT + (size_t)(n0 + r) * E_DIM + kt + k0);
      *reinterpret_cast<uint4*>(Alds + seg * 8) = av;
      *reinterpret_cast<uint4*>(Blds + seg * 8) = bv;
    }
    __syncthreads();
    const int fr = lane & 15, ko = (lane >> 4) * 8;
    bf16x8 af[4], bfr[4];
    #pragma unroll
    for (int i = 0; i < 4; ++i) {
      af[i]  = *reinterpret_cast<const bf16x8*>(&Alds[(wm * 64 + i * 16 + fr) * BK + ko]);
      bfr[i] = *reinterpret_cast<const bf16x8*>(&Blds[(wn * 64 + i * 16 + fr) * BK + ko]);
    }
    #pragma unroll
    for (int i = 0; i < 4; ++i)
      #pragma unroll
      for (int j = 0; j < 4; ++j)
        acc[i][j] = __builtin_amdgcn_mfma_f32_16x16x32_bf16(af[i], bfr[j], acc[i][j], 0, 0, 0);
    __syncthreads();
  }

  // epilogue: C/D layout col = lane&15, row = (lane>>4)*4 + reg   [m89-verified]
  const int colb = lane & 15;
  const int rowb = (lane >> 4) * 4;
  #pragma unroll
  for (int i = 0; i < 4; ++i) {
    const int mbase = m0 + wm * 64 + i * 16 + rowb;
    #pragma unroll
    for (int j = 0; j < 4; ++j) {
      const int ncol = n0 + wn * 64 + j * 16 + colb;
      const float bval = bias[ncol];
      #pragma unroll
      for (int r = 0; r < 4; ++r) {
        const int m = mbase + r;
        const float val = acc[i][j][r] + bval;
        const int b = m >> 11, l = m & 2047, h = ncol >> 6, d = ncol & 63;
        if (MODE == 0) {
          outb[(((size_t)(b * NH + h) * L_SEQ + l) << 6) + d] = f2bf(val);
        } else if (MODE == 1) {
          outf[((size_t)((b * NH + h) * 64 + d)) * L_SEQ + l] = val;
          outb[(((size_t)(b * NH + h) * L_SEQ + l) << 6) + d] = f2bf(val);
        } else if (MODE == 2) {
          outf[(((size_t)(b * NH + h) * L_SEQ + l)) * 64 + d] = val;
          outb[((size_t)(b * NH + h) * 64 + d) * L_SEQ + l] = f2bf(val);
        } else {
          outf[(size_t)m * E_DIM + ncol] = val + extra[(size_t)m * E_DIM + ncol];
        }
      }
    }
  }
}

// ---------------- MFMA flash attention ----------------
// Block = one (b,h) x 64 q rows; 4 waves x 16 q rows; keys tiled by 64 (causal).
// q/k: bf16 (N,H,L,64); vT: bf16 (N,H,64,L). out wv: bf16 (N,L,H*64).
// Swapped QK^T: S^T = mfma(K_frag, Q_frag) -> lane holds S[q=lane&15][key=kt*16+(lane>>4)*4+r].
// P round-trips per-wave LDS (stride 72 bf16 = 2-way bank alias, free) to become PV A-frags.
__global__ __launch_bounds__(256) void attn_mfma(
    const u16* __restrict__ qbf, const u16* __restrict__ kbf,
    const u16* __restrict__ vTb, u16* __restrict__ wv)
{
  __shared__ u16 Klds[64][72];
  __shared__ u16 Vlds[64][72];
  __shared__ u16 Plds[4][16][72];
  const int t = threadIdx.x, lane = t & 63, wave = t >> 6;
  const int bh = blockIdx.x >> 5;          // b*NH + h
  const int qt = blockIdx.x & 31;          // q tile of 64
  const int q0 = qt * 64;
  const int q0w = q0 + wave * 16;
  const int fr = lane & 15, hi = lane >> 4;
  const int qg = q0w + fr;                 // this lane's q row in S^T layout

  const u16* qrow = qbf + ((size_t)bh * L_SEQ + q0w + fr) * 64 + hi * 8;
  const bf16x8 qf0 = *reinterpret_cast<const bf16x8*>(qrow);
  const bf16x8 qf1 = *reinterpret_cast<const bf16x8*>(qrow + 32);

  f32x4 o[4] = {};                         // o[dt][r]: q=hi*4+r, d=dt*16+fr
  float mrun = -3.0e38f, lrun = 0.f;

  const u16* kbase = kbf + (size_t)bh * L_SEQ * 64;
  const u16* vbase = vTb + (size_t)bh * 64 * L_SEQ;

  const int ntiles = qt + 1;
  for (int tkv = 0; tkv < ntiles; ++tkv) {
    const int j0 = tkv * 64;
    // stage K (64 keys x 64 d) and V^T (64 d x 64 keys): 512 x 16B segments each
    #pragma unroll
    for (int s = 0; s < 2; ++s) {
      const int seg = t + s * 256;
      const int r = seg >> 3, c8 = (seg & 7) * 8;   // 8 segments of 8 bf16 per 64-elem row
      *reinterpret_cast<uint4*>(&Klds[r][c8]) =
          *reinterpret_cast<const uint4*>(kbase + (size_t)(j0 + r) * 64 + c8);
      *reinterpret_cast<uint4*>(&Vlds[r][c8]) =
          *reinterpret_cast<const uint4*>(vbase + (size_t)r * L_SEQ + j0 + c8);
    }
    __syncthreads();

    // S^T = K . Q^T
    f32x4 st[4] = {};
    #pragma unroll
    for (int kt = 0; kt < 4; ++kt) {
      bf16x8 ka0 = *reinterpret_cast<const bf16x8*>(&Klds[kt*16 + fr][hi*8]);
      bf16x8 ka1 = *reinterpret_cast<const bf16x8*>(&Klds[kt*16 + fr][32 + hi*8]);
      st[kt] = __builtin_amdgcn_mfma_f32_16x16x32_bf16(ka0, qf0, st[kt], 0, 0, 0);
      st[kt] = __builtin_amdgcn_mfma_f32_16x16x32_bf16(ka1, qf1, st[kt], 0, 0, 0);
    }

    // mask (+(-9999) before /8, as reference) + scale + online softmax
    float p[16];
    float pmax = -3.0e38f;
    #pragma unroll
    for (int kt = 0; kt < 4; ++kt)
      #pragma unroll
      for (int r = 0; r < 4; ++r) {
        const int key = j0 + kt*16 + hi*4 + r;
        const float v = st[kt][r] * 0.125f + (key > qg ? -1249.875f : 0.f);
        p[kt*4 + r] = v;
        pmax = fmaxf(pmax, v);
      }
    pmax = fmaxf(pmax, __shfl_xor(pmax, 16));
    pmax = fmaxf(pmax, __shfl_xor(pmax, 32));
    const float mnew = fmaxf(mrun, pmax);
    const float alpha = __expf(mrun - mnew);
    float lsum = 0.f;
    #pragma unroll
    for (int i = 0; i < 16; ++i) { p[i] = __expf(p[i] - mnew); lsum += p[i]; }
    lsum += __shfl_xor(lsum, 16);
    lsum += __shfl_xor(lsum, 32);
    lrun = lrun * alpha + lsum;
    mrun = mnew;
    #pragma unroll
    for (int r = 0; r < 4; ++r) {
      const float ar = __shfl(alpha, hi*4 + r);
      o[0][r] *= ar; o[1][r] *= ar; o[2][r] *= ar; o[3][r] *= ar;
    }

    // P -> per-wave LDS (bf16), layout P[q=fr][key 0..63]
    #pragma unroll
    for (int kt = 0; kt < 4; ++kt) {
      ushort4 w4;
      w4.x = f2bf(p[kt*4+0]); w4.y = f2bf(p[kt*4+1]);
      w4.z = f2bf(p[kt*4+2]); w4.w = f2bf(p[kt*4+3]);
      *reinterpret_cast<ushort4*>(&Plds[wave][fr][kt*16 + hi*4]) = w4;
    }

    // PV: o += P(16x64) . V(64x64)
    const bf16x8 pf0 = *reinterpret_cast<const bf16x8*>(&Plds[wave][fr][hi*8]);
    const bf16x8 pf1 = *reinterpret_cast<const bf16x8*>(&Plds[wave][fr][32 + hi*8]);
    #pragma unroll
    for (int dt = 0; dt < 4; ++dt) {
      bf16x8 vf0 = *reinterpret_cast<const bf16x8*>(&Vlds[dt*16 + fr][hi*8]);
      bf16x8 vf1 = *reinterpret_cast<const bf16x8*>(&Vlds[dt*16 + fr][32 + hi*8]);
      o[dt] = __builtin_amdgcn_mfma_f32_16x16x32_bf16(pf0, vf0, o[dt], 0, 0, 0);
      o[dt] = __builtin_amdgcn_mfma_f32_16x16x32_bf16(pf1, vf1, o[dt], 0, 0, 0);
    }
    __syncthreads();
  }

  const float inv = 1.f / lrun;
  const int b = bh >> 4, h = bh & 15;
  #pragma unroll
  for (int r = 0; r < 4; ++r) {
    const float ir = __shfl(inv, hi*4 + r);
    const int q = q0w + hi*4 + r;
    u16* dst = wv + (size_t)(b * L_SEQ + q) * E_DIM + h * 64 + fr;
    #pragma unroll
    for (int dt = 0; dt < 4; ++dt)
      dst[dt * 16] = f2bf(o[dt][r] * ir);
  }
}

extern "C" void kernel_launch(void* const* d_in, const int* in_sizes, int n_in,
                              void* d_out, int out_size, void* d_ws, size_t ws_size,
                              hipStream_t stream) {
  (void)in_sizes; (void)n_in; (void)out_size; (void)ws_size;
  const float* tokens = (const float*)d_in[0];
  const float* ln_q_g = (const float*)d_in[1];
  const float* ln_q_b = (const float*)d_in[2];
  const float* Wq     = (const float*)d_in[3];
  const float* bq     = (const float*)d_in[4];
  const float* ln_k_g = (const float*)d_in[5];
  const float* ln_k_b = (const float*)d_in[6];
  const float* Wk     = (const float*)d_in[7];
  const float* bk     = (const float*)d_in[8];
  const float* ln_v_g = (const float*)d_in[9];
  const float* ln_v_b = (const float*)d_in[10];
  const float* Wv     = (const float*)d_in[11];
  const float* bv     = (const float*)d_in[12];
  const float* ln_o_g = (const float*)d_in[13];
  const float* ln_o_b = (const float*)d_in[14];
  const float* Wo     = (const float*)d_in[15];
  const float* bo     = (const float*)d_in[16];

  float* out  = (float*)d_out;            // (2,2048,1024)
  float* kout = out + 4194304;            // (2,16,64,2048)
  float* vout = kout + 4194304;           // (2,16,2048,64)

  char* w = (char*)d_ws;
  const size_t MB = (size_t)1 << 20;
  u16* WTq = (u16*)(w + 0 * MB);
  u16* WTv = (u16*)(w + 2 * MB);
  u16* WTk = (u16*)(w + 4 * MB);
  u16* WTo = (u16*)(w + 6 * MB);
  u16* xq  = (u16*)(w + 8 * MB);    // LN(q) bf16; slot REUSED as kbf after gemm<0>
  u16* xk  = (u16*)(w + 16 * MB);   // LN with ln_v params (feeds k = x @ Wv); REUSED as vTb
  u16* xv  = (u16*)(w + 24 * MB);   // LN with ln_k params (feeds v = x @ Wk)
  u16* qbf = (u16*)(w + 32 * MB);
  u16* wvb = (u16*)(w + 40 * MB);
  u16* lnw = (u16*)(w + 48 * MB);
  u16* kbf = xq;                    // bf16 k (N,H,L,64) — written by gemm<1>, xq dead by then
  u16* vTb = xk;                    // bf16 v^T (N,H,64,L) — written by gemm<2>, xk dead by then

  transpose_w<<<dim3(32, 32), 256, 0, stream>>>(Wq, WTq);
  transpose_w<<<dim3(32, 32), 256, 0, stream>>>(Wv, WTv);
  transpose_w<<<dim3(32, 32), 256, 0, stream>>>(Wk, WTk);
  transpose_w<<<dim3(32, 32), 256, 0, stream>>>(Wo, WTo);
  ln3_kernel<<<M_ROWS, 256, 0, stream>>>(tokens,
      ln_q_g, ln_q_b, xq,
      ln_v_g, ln_v_b, xk,
      ln_k_g, ln_k_b, xv);
  gemm_bt<0><<<dim3(8, 32), 256, 0, stream>>>(xq, WTq, bq, nullptr, qbf, nullptr);
  gemm_bt<1><<<dim3(8, 32), 256, 0, stream>>>(xk, WTv, bv, kout, kbf, nullptr);
  gemm_bt<2><<<dim3(8, 32), 256, 0, stream>>>(xv, WTk, bk, vout, vTb, nullptr);
  attn_mfma<<<32 * 32, 256, 0, stream>>>(qbf, kbf, vTb, wvb);
  ln1_bf_kernel<<<M_ROWS, 256, 0, stream>>>(wvb, ln_o_g, ln_o_b, lnw);
  gemm_bt<3><<<dim3(8, 32), 256, 0, stream>>>(lnw, WTo, bo, out, nullptr, tokens);
}

// Round 4
// 172.475 us; speedup vs baseline: 9.7813x; 1.2841x over previous
//
#include <hip/hip_runtime.h>

#define L_SEQ 2048
#define NH    16
#define E_DIM 1024
#define M_ROWS 4096
#define BK 32

typedef unsigned short u16;
typedef unsigned int   u32;
typedef __attribute__((ext_vector_type(8))) __bf16 bf16x8;
typedef __attribute__((ext_vector_type(4))) float  f32x4;

__device__ __forceinline__ u16 f2bf(float f) {
  union { float f; u32 u; } x; x.f = f;
  u32 u = x.u;
  return (u16)((u + 0x7FFFu + ((u >> 16) & 1u)) >> 16);
}
__device__ __forceinline__ float bf2f(u16 v) {
  union { u32 u; float f; } x; x.u = ((u32)v) << 16;
  return x.f;
}
__device__ __forceinline__ void st_bf4(u16* p, float a, float b, float c, float d) {
  ushort4 u; u.x = f2bf(a); u.y = f2bf(b); u.z = f2bf(c); u.w = f2bf(d);
  *reinterpret_cast<ushort4*>(p) = u;
}
// async global->LDS, 16B per lane; LDS dest must be linear in lane order
__device__ __forceinline__ void gload16(const u16* g, u16* l) {
  __builtin_amdgcn_global_load_lds(
      (const __attribute__((address_space(1))) void*)g,
      (__attribute__((address_space(3))) void*)l, 16, 0, 0);
}

// ---------------- LayerNorm: fp32 input -> 3 bf16 outputs ----------------
__global__ __launch_bounds__(256) void ln3_kernel(
    const float* __restrict__ x,
    const float* __restrict__ g0, const float* __restrict__ b0, u16* __restrict__ o0,
    const float* __restrict__ g1, const float* __restrict__ b1, u16* __restrict__ o1,
    const float* __restrict__ g2, const float* __restrict__ b2, u16* __restrict__ o2)
{
  __shared__ float red[8];
  const size_t row = blockIdx.x;
  const int t = threadIdx.x;
  float4 v = reinterpret_cast<const float4*>(x + row * E_DIM)[t];
  float s = v.x + v.y + v.z + v.w;
  float q = v.x*v.x + v.y*v.y + v.z*v.z + v.w*v.w;
  #pragma unroll
  for (int o = 32; o; o >>= 1) { s += __shfl_down(s, o); q += __shfl_down(q, o); }
  if ((t & 63) == 0) { red[t >> 6] = s; red[4 + (t >> 6)] = q; }
  __syncthreads();
  float S = red[0] + red[1] + red[2] + red[3];
  float Q = red[4] + red[5] + red[6] + red[7];
  float mean = S * (1.f / E_DIM);
  float rstd = rsqrtf(Q * (1.f / E_DIM) - mean * mean + 1e-5f);
  float n0 = (v.x - mean) * rstd, n1 = (v.y - mean) * rstd;
  float n2 = (v.z - mean) * rstd, n3 = (v.w - mean) * rstd;
  const int c = t * 4;
  {
    float4 g = *reinterpret_cast<const float4*>(g0 + c);
    float4 b = *reinterpret_cast<const float4*>(b0 + c);
    st_bf4(o0 + row * E_DIM + c, n0*g.x + b.x, n1*g.y + b.y, n2*g.z + b.z, n3*g.w + b.w);
  }
  {
    float4 g = *reinterpret_cast<const float4*>(g1 + c);
    float4 b = *reinterpret_cast<const float4*>(b1 + c);
    st_bf4(o1 + row * E_DIM + c, n0*g.x + b.x, n1*g.y + b.y, n2*g.z + b.z, n3*g.w + b.w);
  }
  {
    float4 g = *reinterpret_cast<const float4*>(g2 + c);
    float4 b = *reinterpret_cast<const float4*>(b2 + c);
    st_bf4(o2 + row * E_DIM + c, n0*g.x + b.x, n1*g.y + b.y, n2*g.z + b.z, n3*g.w + b.w);
  }
}

// ---------------- LayerNorm: bf16 input -> bf16 output ----------------
__global__ __launch_bounds__(256) void ln1_bf_kernel(
    const u16* __restrict__ x, const float* __restrict__ g,
    const float* __restrict__ b, u16* __restrict__ o)
{
  __shared__ float red[8];
  const size_t row = blockIdx.x;
  const int t = threadIdx.x;
  ushort4 u = reinterpret_cast<const ushort4*>(x + row * E_DIM)[t];
  float v0 = bf2f(u.x), v1 = bf2f(u.y), v2 = bf2f(u.z), v3 = bf2f(u.w);
  float s = v0 + v1 + v2 + v3;
  float q = v0*v0 + v1*v1 + v2*v2 + v3*v3;
  #pragma unroll
  for (int off = 32; off; off >>= 1) { s += __shfl_down(s, off); q += __shfl_down(q, off); }
  if ((t & 63) == 0) { red[t >> 6] = s; red[4 + (t >> 6)] = q; }
  __syncthreads();
  float S = red[0] + red[1] + red[2] + red[3];
  float Q = red[4] + red[5] + red[6] + red[7];
  float mean = S * (1.f / E_DIM);
  float rstd = rsqrtf(Q * (1.f / E_DIM) - mean * mean + 1e-5f);
  const int c = t * 4;
  float4 gg = *reinterpret_cast<const float4*>(g + c);
  float4 bb = *reinterpret_cast<const float4*>(b + c);
  st_bf4(o + row * E_DIM + c,
         (v0 - mean)*rstd*gg.x + bb.x, (v1 - mean)*rstd*gg.y + bb.y,
         (v2 - mean)*rstd*gg.z + bb.z, (v3 - mean)*rstd*gg.w + bb.w);
}

// ---------------- fused weight transposes: W (K x N) -> WT (N x K), 4 weights ----------------
__global__ __launch_bounds__(256) void transpose_all(
    const float* __restrict__ W0, const float* __restrict__ W1,
    const float* __restrict__ W2, const float* __restrict__ W3,
    u16* __restrict__ T0, u16* __restrict__ T1, u16* __restrict__ T2, u16* __restrict__ T3)
{
  __shared__ float tile[32][33];
  const float* W = (blockIdx.z == 0) ? W0 : (blockIdx.z == 1) ? W1 : (blockIdx.z == 2) ? W2 : W3;
  u16* T = (blockIdx.z == 0) ? T0 : (blockIdx.z == 1) ? T1 : (blockIdx.z == 2) ? T2 : T3;
  const int tx = threadIdx.x & 31, ty = threadIdx.x >> 5;
  const int bx = blockIdx.x * 32, by = blockIdx.y * 32;
  #pragma unroll
  for (int r = 0; r < 4; ++r)
    tile[ty + r * 8][tx] = W[(size_t)(by + ty + r * 8) * E_DIM + bx + tx];
  __syncthreads();
  #pragma unroll
  for (int r = 0; r < 4; ++r)
    T[(size_t)(bx + ty + r * 8) * E_DIM + by + tx] = f2bf(tile[tx][ty + r * 8]);
}

// ---------------- shared GEMM mainloop: 128x128 tile, BK=32, global_load_lds staging ----------------
__device__ __forceinline__ void gemm_core(
    const u16* __restrict__ A, const u16* __restrict__ BT,
    int m0, int n0, int t, u16* Alds, u16* Blds, f32x4 (&acc)[4][4])
{
  const int lane = t & 63, wave = t >> 6;
  const int wm = wave >> 1, wn = wave & 1;
  for (int kt = 0; kt < E_DIM; kt += BK) {
    #pragma unroll
    for (int s = 0; s < 2; ++s) {
      const int seg = t + s * 256;            // 512 x 16B segments per tile (128 rows x 32 cols)
      const int r = seg >> 2, k0 = (seg & 3) * 8;
      gload16(A  + (size_t)(m0 + r) * E_DIM + kt + k0, Alds + seg * 8);
      gload16(BT + (size_t)(n0 + r) * E_DIM + kt + k0, Blds + seg * 8);
    }
    __syncthreads();
    const int fr = lane & 15, ko = (lane >> 4) * 8;
    bf16x8 af[4], bfr[4];
    #pragma unroll
    for (int i = 0; i < 4; ++i) {
      af[i]  = *reinterpret_cast<const bf16x8*>(&Alds[(wm * 64 + i * 16 + fr) * BK + ko]);
      bfr[i] = *reinterpret_cast<const bf16x8*>(&Blds[(wn * 64 + i * 16 + fr) * BK + ko]);
    }
    #pragma unroll
    for (int i = 0; i < 4; ++i)
      #pragma unroll
      for (int j = 0; j < 4; ++j)
        acc[i][j] = __builtin_amdgcn_mfma_f32_16x16x32_bf16(af[i], bfr[j], acc[i][j], 0, 0, 0);
    __syncthreads();
  }
}

// ---------------- fused QKV GEMM: z=0 -> q(bf16), z=1 -> k(fp32 T + bf16), z=2 -> v(fp32 + bf16 T) ----------------
__global__ __launch_bounds__(256) void gemm_qkv(
    const u16* __restrict__ xq, const u16* __restrict__ xk, const u16* __restrict__ xv,
    const u16* __restrict__ WTq, const u16* __restrict__ WTv, const u16* __restrict__ WTk,
    const float* __restrict__ bq, const float* __restrict__ bv, const float* __restrict__ bk,
    float* __restrict__ kout, float* __restrict__ vout,
    u16* __restrict__ qbf, u16* __restrict__ kbf, u16* __restrict__ vTb)
{
  __shared__ u16 Alds[128 * BK];
  __shared__ u16 Blds[128 * BK];
  const int z = blockIdx.z;
  const u16* A  = (z == 0) ? xq  : (z == 1) ? xk  : xv;
  const u16* BT = (z == 0) ? WTq : (z == 1) ? WTv : WTk;
  const float* bias = (z == 0) ? bq : (z == 1) ? bv : bk;
  const int t = threadIdx.x;
  const int m0 = blockIdx.y * 128, n0 = blockIdx.x * 128;
  f32x4 acc[4][4] = {};
  gemm_core(A, BT, m0, n0, t, Alds, Blds, acc);

  const int lane = t & 63, wave = t >> 6;
  const int wm = wave >> 1, wn = wave & 1;
  const int colb = lane & 15, rowb = (lane >> 4) * 4;
  #pragma unroll
  for (int i = 0; i < 4; ++i) {
    const int mbase = m0 + wm * 64 + i * 16 + rowb;
    #pragma unroll
    for (int j = 0; j < 4; ++j) {
      const int ncol = n0 + wn * 64 + j * 16 + colb;
      const float bval = bias[ncol];
      #pragma unroll
      for (int r = 0; r < 4; ++r) {
        const int m = mbase + r;
        const float val = acc[i][j][r] + bval;
        const int b = m >> 11, l = m & 2047, h = ncol >> 6, d = ncol & 63;
        const size_t bh = (size_t)(b * NH + h);
        if (z == 0) {
          qbf[((bh * L_SEQ + l) << 6) + d] = f2bf(val);
        } else if (z == 1) {
          kout[(bh * 64 + d) * L_SEQ + l] = val;
          kbf[((bh * L_SEQ + l) << 6) + d] = f2bf(val);
        } else {
          vout[(bh * L_SEQ + l) * 64 + d] = val;
          vTb[(bh * 64 + d) * L_SEQ + l] = f2bf(val);
        }
      }
    }
  }
}

// ---------------- final GEMM: out = lnw @ Wo + bo + tokens ----------------
__global__ __launch_bounds__(256) void gemm_o(
    const u16* __restrict__ A, const u16* __restrict__ BT, const float* __restrict__ bias,
    const float* __restrict__ tokens, float* __restrict__ out)
{
  __shared__ u16 Alds[128 * BK];
  __shared__ u16 Blds[128 * BK];
  const int t = threadIdx.x;
  const int m0 = blockIdx.y * 128, n0 = blockIdx.x * 128;
  f32x4 acc[4][4] = {};
  gemm_core(A, BT, m0, n0, t, Alds, Blds, acc);

  const int lane = t & 63, wave = t >> 6;
  const int wm = wave >> 1, wn = wave & 1;
  const int colb = lane & 15, rowb = (lane >> 4) * 4;
  #pragma unroll
  for (int i = 0; i < 4; ++i) {
    const int mbase = m0 + wm * 64 + i * 16 + rowb;
    #pragma unroll
    for (int j = 0; j < 4; ++j) {
      const int ncol = n0 + wn * 64 + j * 16 + colb;
      const float bval = bias[ncol];
      #pragma unroll
      for (int r = 0; r < 4; ++r) {
        const int m = mbase + r;
        out[(size_t)m * E_DIM + ncol] = acc[i][j][r] + bval + tokens[(size_t)m * E_DIM + ncol];
      }
    }
  }
}

// ---------------- MFMA flash attention, q-tile-paired for causal balance ----------------
// Block = one (b,h) x TWO q-tiles (qt = pr and 31-pr): exactly 33 kv-tile iterations each.
// 4 waves x 16 q rows. q/k: bf16 (N,H,L,64); vT: bf16 (N,H,64,L). out wv: bf16 (N,L,H*64).
// Swapped QK^T: S^T = mfma(K,Q) -> lane holds S[q=lane&15][key=kt*16+(lane>>4)*4+r].
__global__ __launch_bounds__(256) void attn_mfma(
    const u16* __restrict__ qbf, const u16* __restrict__ kbf,
    const u16* __restrict__ vTb, u16* __restrict__ wv)
{
  __shared__ u16 Klds[64][72];
  __shared__ u16 Vlds[64][72];
  __shared__ u16 Plds[4][16][72];
  const int t = threadIdx.x, lane = t & 63, wave = t >> 6;
  const int bi = blockIdx.x;
  // XCD grouping: HW assigns XCD = launched_id % 8; keep each bh's 16 blocks on one XCD
  const int bh = (bi & 7) + 8 * ((bi >> 3) & 3);   // b*NH + h
  const int pr = bi >> 5;                          // pair index 0..15
  const int fr = lane & 15, hi = lane >> 4;
  const u16* kbase = kbf + (size_t)bh * L_SEQ * 64;
  const u16* vbase = vTb + (size_t)bh * 64 * L_SEQ;
  const int b = bh >> 4, h = bh & 15;

  #pragma unroll 1
  for (int half = 0; half < 2; ++half) {
    const int qt = half ? (31 - pr) : pr;
    const int q0w = qt * 64 + wave * 16;
    const int qg = q0w + fr;

    const u16* qrow = qbf + ((size_t)bh * L_SEQ + q0w + fr) * 64 + hi * 8;
    const bf16x8 qf0 = *reinterpret_cast<const bf16x8*>(qrow);
    const bf16x8 qf1 = *reinterpret_cast<const bf16x8*>(qrow + 32);

    f32x4 o[4] = {};
    float mrun = -3.0e38f, lrun = 0.f;

    for (int tkv = 0; tkv <= qt; ++tkv) {
      const int j0 = tkv * 64;
      const bool diag = (tkv == qt);
      #pragma unroll
      for (int s = 0; s < 2; ++s) {
        const int seg = t + s * 256;
        const int r = seg >> 3, c8 = (seg & 7) * 8;
        *reinterpret_cast<uint4*>(&Klds[r][c8]) =
            *reinterpret_cast<const uint4*>(kbase + (size_t)(j0 + r) * 64 + c8);
        *reinterpret_cast<uint4*>(&Vlds[r][c8]) =
            *reinterpret_cast<const uint4*>(vbase + (size_t)r * L_SEQ + j0 + c8);
      }
      __syncthreads();

      // S^T = K . Q^T
      f32x4 st[4] = {};
      #pragma unroll
      for (int kt = 0; kt < 4; ++kt) {
        bf16x8 ka0 = *reinterpret_cast<const bf16x8*>(&Klds[kt*16 + fr][hi*8]);
        bf16x8 ka1 = *reinterpret_cast<const bf16x8*>(&Klds[kt*16 + fr][32 + hi*8]);
        st[kt] = __builtin_amdgcn_mfma_f32_16x16x32_bf16(ka0, qf0, st[kt], 0, 0, 0);
        st[kt] = __builtin_amdgcn_mfma_f32_16x16x32_bf16(ka1, qf1, st[kt], 0, 0, 0);
      }

      // mask (diag tile only) + scale + online softmax
      float p[16];
      float pmax = -3.0e38f;
      #pragma unroll
      for (int kt = 0; kt < 4; ++kt)
        #pragma unroll
        for (int r = 0; r < 4; ++r) {
          const int key = j0 + kt*16 + hi*4 + r;
          const float v = st[kt][r] * 0.125f +
                          ((diag && key > qg) ? -1249.875f : 0.f);
          p[kt*4 + r] = v;
          pmax = fmaxf(pmax, v);
        }
      pmax = fmaxf(pmax, __shfl_xor(pmax, 16));
      pmax = fmaxf(pmax, __shfl_xor(pmax, 32));
      const float mnew = fmaxf(mrun, pmax);
      const float alpha = __expf(mrun - mnew);
      float lsum = 0.f;
      #pragma unroll
      for (int i = 0; i < 16; ++i) { p[i] = __expf(p[i] - mnew); lsum += p[i]; }
      lsum += __shfl_xor(lsum, 16);
      lsum += __shfl_xor(lsum, 32);
      lrun = lrun * alpha + lsum;
      mrun = mnew;
      #pragma unroll
      for (int r = 0; r < 4; ++r) {
        const float ar = __shfl(alpha, hi*4 + r);
        o[0][r] *= ar; o[1][r] *= ar; o[2][r] *= ar; o[3][r] *= ar;
      }

      // P -> per-wave LDS (bf16), layout P[q=fr][key 0..63]
      #pragma unroll
      for (int kt = 0; kt < 4; ++kt) {
        ushort4 w4;
        w4.x = f2bf(p[kt*4+0]); w4.y = f2bf(p[kt*4+1]);
        w4.z = f2bf(p[kt*4+2]); w4.w = f2bf(p[kt*4+3]);
        *reinterpret_cast<ushort4*>(&Plds[wave][fr][kt*16 + hi*4]) = w4;
      }

      // PV: o += P(16x64) . V(64x64)
      const bf16x8 pf0 = *reinterpret_cast<const bf16x8*>(&Plds[wave][fr][hi*8]);
      const bf16x8 pf1 = *reinterpret_cast<const bf16x8*>(&Plds[wave][fr][32 + hi*8]);
      #pragma unroll
      for (int dt = 0; dt < 4; ++dt) {
        bf16x8 vf0 = *reinterpret_cast<const bf16x8*>(&Vlds[dt*16 + fr][hi*8]);
        bf16x8 vf1 = *reinterpret_cast<const bf16x8*>(&Vlds[dt*16 + fr][32 + hi*8]);
        o[dt] = __builtin_amdgcn_mfma_f32_16x16x32_bf16(pf0, vf0, o[dt], 0, 0, 0);
        o[dt] = __builtin_amdgcn_mfma_f32_16x16x32_bf16(pf1, vf1, o[dt], 0, 0, 0);
      }
      __syncthreads();
    }

    const float inv = 1.f / lrun;
    #pragma unroll
    for (int r = 0; r < 4; ++r) {
      const float ir = __shfl(inv, hi*4 + r);
      const int q = q0w + hi*4 + r;
      u16* dst = wv + (size_t)(b * L_SEQ + q) * E_DIM + h * 64 + fr;
      #pragma unroll
      for (int dt = 0; dt < 4; ++dt)
        dst[dt * 16] = f2bf(o[dt][r] * ir);
    }
  }
}

extern "C" void kernel_launch(void* const* d_in, const int* in_sizes, int n_in,
                              void* d_out, int out_size, void* d_ws, size_t ws_size,
                              hipStream_t stream) {
  (void)in_sizes; (void)n_in; (void)out_size; (void)ws_size;
  const float* tokens = (const float*)d_in[0];
  const float* ln_q_g = (const float*)d_in[1];
  const float* ln_q_b = (const float*)d_in[2];
  const float* Wq     = (const float*)d_in[3];
  const float* bq     = (const float*)d_in[4];
  const float* ln_k_g = (const float*)d_in[5];
  const float* ln_k_b = (const float*)d_in[6];
  const float* Wk     = (const float*)d_in[7];
  const float* bk     = (const float*)d_in[8];
  const float* ln_v_g = (const float*)d_in[9];
  const float* ln_v_b = (const float*)d_in[10];
  const float* Wv     = (const float*)d_in[11];
  const float* bv     = (const float*)d_in[12];
  const float* ln_o_g = (const float*)d_in[13];
  const float* ln_o_b = (const float*)d_in[14];
  const float* Wo     = (const float*)d_in[15];
  const float* bo     = (const float*)d_in[16];

  float* out  = (float*)d_out;            // (2,2048,1024)
  float* kout = out + 4194304;            // (2,16,64,2048)
  float* vout = kout + 4194304;           // (2,16,2048,64)

  char* w = (char*)d_ws;
  const size_t MB = (size_t)1 << 20;
  u16* WTq = (u16*)(w + 0 * MB);
  u16* WTv = (u16*)(w + 2 * MB);
  u16* WTk = (u16*)(w + 4 * MB);
  u16* WTo = (u16*)(w + 6 * MB);
  u16* xq  = (u16*)(w + 8 * MB);    // LN(q) bf16; REUSED as wvb after gemm_qkv
  u16* xk  = (u16*)(w + 16 * MB);   // LN(ln_v) bf16 (feeds k=x@Wv); REUSED as lnw after gemm_qkv
  u16* xv  = (u16*)(w + 24 * MB);   // LN(ln_k) bf16 (feeds v=x@Wk)
  u16* qbf = (u16*)(w + 32 * MB);   // q bf16 (N,H,L,64)
  u16* kbf = (u16*)(w + 40 * MB);   // k bf16 (N,H,L,64)
  u16* vTb = (u16*)(w + 48 * MB);   // v^T bf16 (N,H,64,L)
  u16* wvb = xq;                    // attn out (N,L,E) — xq dead after gemm_qkv
  u16* lnw = xk;                    // LN(wv)    — xk dead after gemm_qkv

  transpose_all<<<dim3(32, 32, 4), 256, 0, stream>>>(Wq, Wv, Wk, Wo, WTq, WTv, WTk, WTo);
  ln3_kernel<<<M_ROWS, 256, 0, stream>>>(tokens,
      ln_q_g, ln_q_b, xq,
      ln_v_g, ln_v_b, xk,
      ln_k_g, ln_k_b, xv);
  gemm_qkv<<<dim3(8, 32, 3), 256, 0, stream>>>(xq, xk, xv, WTq, WTv, WTk,
      bq, bv, bk, kout, vout, qbf, kbf, vTb);
  attn_mfma<<<512, 256, 0, stream>>>(qbf, kbf, vTb, wvb);
  ln1_bf_kernel<<<M_ROWS, 256, 0, stream>>>(wvb, ln_o_g, ln_o_b, lnw);
  gemm_o<<<dim3(8, 32), 256, 0, stream>>>(lnw, WTo, bo, tokens, out);
}